// Round 7
// baseline (1767.698 us; speedup 1.0000x reference)
//
#include <hip/hip_runtime.h>
#include <hip/hip_cooperative_groups.h>
namespace cg = cooperative_groups;

#define BATCH 32
#define TT 8
#define VOCAB 2048
#define EMB 256
#define NG 8192          // 4*VOCAB
#define LAT 128
#define KTOT 2304        // EMB + VOCAB
#define NKT 72           // KTOT/32 k-tiles
#define NNT 512          // NG/16 n-tiles
#define KSPLIT 8
#define KT_PER 9         // NKT/KSPLIT
#define NTHR 256
#define NWORK 1024       // gemm tiles per step == cell units per step

typedef __bf16 bf16x8 __attribute__((ext_vector_type(8)));
typedef float  f32x4  __attribute__((ext_vector_type(4)));

// ws layout (float offsets)
#define P_OFF   0
#define P_SZ    (KSPLIT*BATCH*NG)     // 8 MB
#define H_OFF   (P_OFF + P_SZ)
#define H_SZ    (BATCH*VOCAB)
#define C_OFF   (H_OFF + H_SZ)
#define C_SZ    (BATCH*VOCAB)
#define ST_OFF  (C_OFF + C_SZ)
#define ST_SZ   (BATCH*32*2)          // per-(b,jq) partial {Z,S}
#define ESJ_OFF (ST_OFF + ST_SZ)
#define ESJ_SZ  32
#define AHB_OFF (ESJ_OFF + ESJ_SZ)    // ushort region: 32*2304
#define AHB_SZF ((BATCH*KTOT)/2)
#define BP_OFF  (AHB_OFF + AHB_SZF)   // ushort region: 512*72*64*8 (~37.7MB)

__device__ __forceinline__ float sigmoidf_(float x){ return 1.f/(1.f+__expf(-x)); }
__device__ __forceinline__ float tanhf_(float x){
  x = fminf(fmaxf(x, -10.f), 10.f);
  float e = __expf(2.f*x);
  return (e-1.f)/(e+1.f);
}
__device__ __forceinline__ unsigned short f2bf(float f){   // round-to-nearest-even
  unsigned int u = __float_as_uint(f);
  return (unsigned short)((u + 0x7FFFu + ((u>>16)&1u)) >> 16);
}

// ---------- phase device functions (shared by coop + fallback paths) ----------

__device__ __forceinline__ void pack_one(size_t g,
    const float* __restrict__ Wi, const float* __restrict__ Wh,
    unsigned short* __restrict__ Bp){
  int lane = (int)(g & 63), kt = (int)((g>>6) % NKT), nt = (int)(g/(64*NKT));
  int n = nt*16 + (lane & 15);
  int k0 = kt*32 + (lane>>4)*8;
  unsigned int u[4];
  #pragma unroll
  for (int p=0;p<4;p++){
    int ka = k0 + 2*p, kb = k0 + 2*p + 1;
    float fa = (ka < EMB) ? Wi[(size_t)ka*NG + n] : Wh[(size_t)(ka-EMB)*NG + n];
    float fb = (kb < EMB) ? Wi[(size_t)kb*NG + n] : Wh[(size_t)(kb-EMB)*NG + n];
    u[p] = (unsigned int)f2bf(fa) | ((unsigned int)f2bf(fb) << 16);
  }
  *(uint4*)&Bp[g*8] = make_uint4(u[0],u[1],u[2],u[3]);
}

// One M=32 x N=16 k-slice tile. wrk in [0,1024): kc = wrk&7 (XCD-pinned slice),
// nt = (wrk>>3)*4 + wave.  B-fragments preloaded (9 outstanding loads).
__device__ __forceinline__ void gemm_tile(int wrk, int tid,
    const unsigned short* __restrict__ Ahb, const unsigned short* __restrict__ Bp,
    float* __restrict__ P){
  const int w = tid>>6, lane = tid&63, quad = lane>>4, col = lane&15;
  const int kc = wrk & 7;
  const int nt = (wrk>>3)*4 + w;
  const int kt0 = kc*KT_PER;
  const bf16x8* __restrict__ AhV = (const bf16x8*)Ahb;  // m*288 + kt*4 + quad
  const bf16x8* __restrict__ BpV = (const bf16x8*)Bp;   // (nt*NKT+kt)*64 + lane
  bf16x8 bfr[KT_PER];
  #pragma unroll
  for (int i=0;i<KT_PER;i++) bfr[i] = BpV[(size_t)(nt*NKT + kt0+i)*64 + lane];
  f32x4 acc0={0,0,0,0}, acc1={0,0,0,0};
  const int a0b = col*(KTOT/8), a1b = (16+col)*(KTOT/8);
  #pragma unroll
  for (int i=0;i<KT_PER;i++){
    bf16x8 a0 = AhV[a0b + (kt0+i)*4 + quad];
    bf16x8 a1 = AhV[a1b + (kt0+i)*4 + quad];
    acc0 = __builtin_amdgcn_mfma_f32_16x16x32_bf16(a0,bfr[i],acc0,0,0,0);
    acc1 = __builtin_amdgcn_mfma_f32_16x16x32_bf16(a1,bfr[i],acc1,0,0,0);
  }
  float* Pp = P + (size_t)kc*BATCH*NG;
  const int rowd = quad*4;
  #pragma unroll
  for (int r=0;r<4;r++){
    Pp[(size_t)(rowd+r)*NG    + nt*16 + col] = acc0[r];
    Pp[(size_t)(16+rowd+r)*NG + nt*16 + col] = acc1[r];
  }
}

// One (b, jq) cell unit: reduce 8 slabs + bias -> gates -> masked LSTM cell ->
// h,c,Ahb -> partial softmax stats. gsh is per-block scratch [4][64].
__device__ __forceinline__ void cell_unit(int wrk, int tid, float (*gsh)[64],
    const int* __restrict__ tok, const float* __restrict__ E,
    const float* __restrict__ bias, const float* __restrict__ P,
    float* __restrict__ h, float* __restrict__ c,
    unsigned short* __restrict__ Ahb, float* __restrict__ stats,
    float* __restrict__ esj, int t){
  const int b = wrk >> 5, jq = wrk & 31;
  const int w = tid >> 6, lane = tid & 63;
  const int j = jq*64 + lane;
  float v = bias[w*VOCAB + j];
  #pragma unroll
  for (int kc=0;kc<KSPLIT;kc++)
    v += P[(size_t)(kc*BATCH + b)*NG + w*VOCAB + j];
  gsh[w][lane] = v;
  __syncthreads();
  if (tid < 64){
    float ip=gsh[0][lane], fp=gsh[1][lane], gg=gsh[2][lane], op=gsh[3][lane];
    float cold = c[b*VOCAB + j];
    float cn = sigmoidf_(fp)*cold + sigmoidf_(ip)*tanhf_(gg);
    float hn = sigmoidf_(op)*tanhf_(cn);
    const bool upd = tok[b*TT + (t-1)] != 0;
    float hf = upd ? hn : h[b*VOCAB + j];
    float cf = upd ? cn : cold;
    h[b*VOCAB + j] = hf;
    c[b*VOCAB + j] = cf;
    Ahb[b*KTOT + EMB + j] = f2bf(hf);
    const int sj = tok[b*TT + t];
    float e = __expf(hf);               // h in (-1,1): no max-pass needed
    if (j == sj) esj[b] = e;
    float z = e, s = (j < sj) ? e : 0.f;
    #pragma unroll
    for (int off=32; off; off>>=1){ z += __shfl_down(z, off); s += __shfl_down(s, off); }
    if (lane==0){
      stats[(b*32 + jq)*2 + 0] = z;
      stats[(b*32 + jq)*2 + 1] = s;
    }
  }
  if (jq==0 && t < TT-1)                 // stage next step's x-row
    Ahb[b*KTOT + tid] = f2bf(E[(size_t)tok[b*TT + t]*EMB + tid]);
  __syncthreads();                       // gsh reused by next work item
}

__device__ __forceinline__ void finalize_out(int tid, float* vsh,
    const float* __restrict__ stats, const float* __restrict__ esj,
    float* __restrict__ out, int tprev){
  if (tid < BATCH){
    float Z=0.f, S=0.f;
    #pragma unroll
    for (int jq=0;jq<32;jq++){ Z += stats[(tid*32+jq)*2]; S += stats[(tid*32+jq)*2+1]; }
    vsh[tid] = (3.f*S + 1.5f*esj[tid])/Z;
  }
  __syncthreads();
  for (int i=tid; i<BATCH*LAT; i+=NTHR)
    out[(size_t)((i>>7)*TT + tprev)*LAT + (i&(LAT-1))] = vsh[i>>7];
}

// ---------------------------- cooperative path ----------------------------

__global__ __launch_bounds__(NTHR, 4) void k_fused(
    const int* __restrict__ tok, const float* __restrict__ E,
    const float* __restrict__ Wi, const float* __restrict__ Wh,
    const float* __restrict__ bias, float* __restrict__ out,
    float* __restrict__ P, float* __restrict__ h, float* __restrict__ c,
    float* __restrict__ stats, float* __restrict__ esj,
    unsigned short* __restrict__ Ahb, unsigned short* __restrict__ Bp){
  cg::grid_group grid = cg::this_grid();
  const int tid = threadIdx.x;
  const int blk = blockIdx.x;
  const int G = gridDim.x;
  const size_t stride = (size_t)G*NTHR;
  const size_t gbase = (size_t)blk*NTHR + tid;

  __shared__ float gsh[4][64];
  __shared__ float vsh[BATCH];

  // Phase 0: pack W + init state
  for (size_t g = gbase; g < (size_t)NNT*NKT*64; g += stride)
    pack_one(g, Wi, Wh, Bp);
  for (size_t i = gbase; i < BATCH*VOCAB; i += stride){ h[i]=0.f; c[i]=0.f; }
  for (size_t i = gbase; i < BATCH*KTOT; i += stride){
    int b = (int)(i / KTOT), k = (int)(i % KTOT);
    Ahb[i] = (k < EMB) ? f2bf(E[(size_t)tok[b*TT+0]*EMB + k]) : (unsigned short)0;
  }
  for (size_t i = gbase; i < BATCH*LAT; i += stride){
    int b = (int)(i >> 7), l = (int)(i & (LAT-1));
    out[(size_t)(b*TT + 0)*LAT + l] = 0.f;   // t=0: rng=0 -> z=0 exactly
  }
  __threadfence();
  grid.sync();

  for (int t = 1; t < TT; t++){
    if (blk==0 && t>=2) finalize_out(tid, vsh, stats, esj, out, t-1);
    for (int wrk = blk; wrk < NWORK; wrk += G)
      gemm_tile(wrk, tid, Ahb, Bp, P);
    __threadfence();
    grid.sync();
    for (int wrk = blk; wrk < NWORK; wrk += G)
      cell_unit(wrk, tid, gsh, tok, E, bias, P, h, c, Ahb, stats, esj, t);
    __threadfence();
    grid.sync();
  }
  if (blk==0) finalize_out(tid, vsh, stats, esj, out, TT-1);
}

// ---------------------------- fallback path ----------------------------

__global__ __launch_bounds__(NTHR) void k_init(
    const int* __restrict__ tok, const float* __restrict__ E,
    float* __restrict__ h, float* __restrict__ c,
    unsigned short* __restrict__ Ahb, float* __restrict__ out){
  int i = blockIdx.x*NTHR + threadIdx.x;
  if (i < BATCH*VOCAB){ h[i] = 0.f; c[i] = 0.f; }
  if (i < BATCH*KTOT){
    int b = i / KTOT, k = i % KTOT;
    Ahb[i] = (k < EMB) ? f2bf(E[(size_t)tok[b*TT+0]*EMB + k]) : (unsigned short)0;
  }
  if (i < BATCH*LAT){
    int b = i >> 7, l = i & (LAT-1);
    out[(size_t)(b*TT + 0)*LAT + l] = 0.f;
  }
}

__global__ __launch_bounds__(NTHR) void k_pack(
    const float* __restrict__ Wi, const float* __restrict__ Wh,
    unsigned short* __restrict__ Bp){
  pack_one((size_t)blockIdx.x*NTHR + threadIdx.x, Wi, Wh, Bp);
}

__global__ __launch_bounds__(NTHR, 4) void k_gemm(
    const unsigned short* __restrict__ Ahb, const unsigned short* __restrict__ Bp,
    float* __restrict__ P, const float* __restrict__ stats,
    const float* __restrict__ esj, float* __restrict__ out, int t){
  const int tid = threadIdx.x;
  if (blockIdx.x==0 && t>=2){
    __shared__ float vsh[BATCH];
    finalize_out(tid, vsh, stats, esj, out, t-1);
  }
  gemm_tile(blockIdx.x, tid, Ahb, Bp, P);
}

__global__ __launch_bounds__(NTHR) void k_cell(
    const int* __restrict__ tok, const float* __restrict__ E,
    const float* __restrict__ bias, const float* __restrict__ P,
    float* __restrict__ h, float* __restrict__ c, unsigned short* __restrict__ Ahb,
    float* __restrict__ stats, float* __restrict__ esj, int t){
  __shared__ float gsh[4][64];
  cell_unit(blockIdx.x, threadIdx.x, gsh, tok, E, bias, P, h, c, Ahb, stats, esj, t);
}

__global__ __launch_bounds__(NTHR) void k_out(
    const float* __restrict__ stats, const float* __restrict__ esj,
    float* __restrict__ out, int t){
  __shared__ float vsh[BATCH];
  finalize_out(threadIdx.x, vsh, stats, esj, out, t);
}

// ---------------------------- host ----------------------------

extern "C" void kernel_launch(void* const* d_in, const int* in_sizes, int n_in,
                              void* d_out, int out_size, void* d_ws, size_t ws_size,
                              hipStream_t stream){
  const int*   tok  = (const int*)d_in[0];
  const float* E    = (const float*)d_in[1];
  const float* Wi   = (const float*)d_in[2];
  const float* Wh   = (const float*)d_in[3];
  const float* bias = (const float*)d_in[4];
  float* out = (float*)d_out;
  float* ws  = (float*)d_ws;
  float* P     = ws + P_OFF;
  float* h     = ws + H_OFF;
  float* c     = ws + C_OFF;
  float* stats = ws + ST_OFF;
  float* esj   = ws + ESJ_OFF;
  unsigned short* Ahb = (unsigned short*)(ws + AHB_OFF);
  unsigned short* Bp  = (unsigned short*)(ws + BP_OFF);

  // Size the cooperative grid from the runtime's own occupancy answer
  // (host-only queries: capture-safe, deterministic across calls).
  int coopOK = 0, dev = 0;
  (void)hipGetDevice(&dev);
  (void)hipDeviceGetAttribute(&coopOK, hipDeviceAttributeCooperativeLaunch, dev);
  int occ = 0;
  (void)hipOccupancyMaxActiveBlocksPerMultiprocessor(&occ, k_fused, NTHR, 0);
  int G = occ * 256;                  // 256 CUs on MI355X
  if (G > NWORK) G = NWORK;

  if (coopOK && G >= 8){
    void* args[] = {(void*)&tok, (void*)&E, (void*)&Wi, (void*)&Wh, (void*)&bias,
                    (void*)&out, (void*)&P, (void*)&h, (void*)&c, (void*)&stats,
                    (void*)&esj, (void*)&Ahb, (void*)&Bp};
    hipLaunchCooperativeKernel((void*)k_fused, dim3(G), dim3(NTHR), args, 0, stream);
  } else {
    k_init<<<288, NTHR, 0, stream>>>(tok, E, h, c, Ahb, out);
    k_pack<<<(NNT*NKT*64)/NTHR, NTHR, 0, stream>>>(Wi, Wh, Bp);
    for (int t = 1; t < TT; t++){
      k_gemm<<<NWORK, NTHR, 0, stream>>>(Ahb, Bp, P, stats, esj, out, t);
      k_cell<<<NWORK, NTHR, 0, stream>>>(tok, E, bias, P, h, c, Ahb, stats, esj, t);
    }
    k_out<<<1, NTHR, 0, stream>>>(stats, esj, out, TT-1);
  }
}

// Round 8
// 1610.006 us; speedup vs baseline: 1.0979x; 1.0979x over previous
//
#include <hip/hip_runtime.h>

#define BATCH 32
#define TT 8
#define VOCAB 2048
#define EMB 256
#define NG 8192          // 4*VOCAB
#define LAT 128
#define KTOT 2304        // EMB + VOCAB
#define NKT 72           // K-tiles of 32
#define NNT 512          // N-tiles of 16
#define NJT 128          // j-tiles of 16 (VOCAB/16)
#define KSPLIT 8
#define KT_SL 9          // NKT/KSPLIT
#define NTHR 256

typedef __bf16 bf16x8 __attribute__((ext_vector_type(8)));
typedef float  f32x4  __attribute__((ext_vector_type(4)));

// ws layout (float offsets)
#define P_OFF   0
#define P_SZ    (NJT*KSPLIT*4*512)    // 2,097,152 f (8 MB) partial gate slabs
#define H_OFF   (P_OFF + P_SZ)
#define H_SZ    (BATCH*VOCAB)
#define C_OFF   (H_OFF + H_SZ)
#define C_SZ    (BATCH*VOCAB)
#define ZAC_OFF (C_OFF + C_SZ)
#define SAC_OFF (ZAC_OFF + 7*32)
#define EAC_OFF (SAC_OFF + 7*32)
#define CNT_OFF (EAC_OFF + 7*32)      // int region: 7*128 arrival counters
#define CNT2_OFF (CNT_OFF + 7*128)    // int region: 7 reducer counters
#define AHB_OFF (CNT2_OFF + 32)       // ushort region: 32*2304
#define AHB_SZF ((BATCH*KTOT)/2)
#define BP_OFF  (AHB_OFF + AHB_SZF)   // ushort region: 512*72*64*8 (~37.7MB)

__device__ __forceinline__ float sigmoidf_(float x){ return 1.f/(1.f+__expf(-x)); }
__device__ __forceinline__ float tanhf_(float x){
  x = fminf(fmaxf(x, -10.f), 10.f);
  float e = __expf(2.f*x);
  return (e-1.f)/(e+1.f);
}
__device__ __forceinline__ unsigned short f2bf(float f){   // round-to-nearest-even
  unsigned int u = __float_as_uint(f);
  return (unsigned short)((u + 0x7FFFu + ((u>>16)&1u)) >> 16);
}

// Zero state/counters, stage x0, out[:,0,:]=0
__global__ __launch_bounds__(NTHR) void k_init(
    const int* __restrict__ tok, const float* __restrict__ E,
    float* __restrict__ h, float* __restrict__ c,
    float* __restrict__ Zac, float* __restrict__ Sac, float* __restrict__ Eac,
    int* __restrict__ cnt, int* __restrict__ cnt2,
    unsigned short* __restrict__ Ahb, float* __restrict__ out){
  int i = blockIdx.x*NTHR + threadIdx.x;
  if (i < BATCH*VOCAB){ h[i] = 0.f; c[i] = 0.f; }
  if (i < BATCH*KTOT){
    int b = i / KTOT, k = i % KTOT;
    Ahb[i] = (k < EMB) ? f2bf(E[(size_t)tok[b*TT+0]*EMB + k]) : (unsigned short)0;
  }
  if (i < BATCH*LAT)
    out[(size_t)((i>>7)*TT + 0)*LAT + (i&(LAT-1))] = 0.f;  // t=0: rng=0 -> z=0
  if (i < 7*32){ Zac[i] = 0.f; Sac[i] = 0.f; Eac[i] = 0.f; }
  if (i < 7*NJT) cnt[i] = 0;
  if (i < 7) cnt2[i] = 0;
}

// One LSTM step. Block (jt,kq): 4 waves = 4 gates, M=32 (batch) x N=16 (j-tile),
// K-slice kq (9 k-tiles). Last-arriving block per jt reduces + runs the cell;
// last reducer block writes out[:,t,:]. t==1 additionally packs its own
// B-slice from fp32 Wi/Wh into Bp (and uses it from registers).
__global__ __launch_bounds__(NTHR) void k_step(
    const int* __restrict__ tok, const float* __restrict__ E,
    const float* __restrict__ Wi, const float* __restrict__ Wh,
    const float* __restrict__ bias, float* __restrict__ out,
    float* __restrict__ P, float* __restrict__ h, float* __restrict__ c,
    float* __restrict__ Zac, float* __restrict__ Sac, float* __restrict__ Eac,
    int* __restrict__ cnt, int* __restrict__ cnt2,
    unsigned short* __restrict__ Ahb, unsigned short* __restrict__ Bp, int t){
  const int tid = threadIdx.x;
  const int w = tid >> 6, lane = tid & 63;
  const int quad = lane >> 4, col = lane & 15;
  const int jt = blockIdx.x >> 3, kq = blockIdx.x & 7;
  const int slot = t - 1;
  const int g = w;                      // gate index = wave
  const int nt = g*128 + jt;            // N-tile in the 8192-wide gate matrix
  const int kt0 = kq*KT_SL;

  __shared__ int isred, isfin;
  __shared__ float vsh[BATCH];

  // ---- B fragments: pack (t==1) or load ----
  union { uint4 u4; bf16x8 v; } bfr[KT_SL];
  const bf16x8* __restrict__ BpV = (const bf16x8*)Bp;
  if (t == 1){
    const int n = nt*16 + col;
    #pragma unroll
    for (int i=0;i<KT_SL;i++){
      int k0 = (kt0+i)*32 + quad*8;
      unsigned int u[4];
      #pragma unroll
      for (int p=0;p<4;p++){
        int ka = k0 + 2*p, kb = ka + 1;
        float fa = (ka < EMB) ? Wi[(size_t)ka*NG + n] : Wh[(size_t)(ka-EMB)*NG + n];
        float fb = (kb < EMB) ? Wi[(size_t)kb*NG + n] : Wh[(size_t)(kb-EMB)*NG + n];
        u[p] = (unsigned int)f2bf(fa) | ((unsigned int)f2bf(fb) << 16);
      }
      bfr[i].u4 = make_uint4(u[0],u[1],u[2],u[3]);
      *(uint4*)&Bp[(((size_t)nt*NKT + kt0+i)*64 + lane)*8] = bfr[i].u4;
    }
  } else {
    #pragma unroll
    for (int i=0;i<KT_SL;i++)
      bfr[i].v = BpV[((size_t)nt*NKT + kt0+i)*64 + lane];
  }

  // ---- MFMA K-slice ----
  const bf16x8* __restrict__ AhV = (const bf16x8*)Ahb;   // idx m*288 + kt*4 + quad
  f32x4 acc0={0,0,0,0}, acc1={0,0,0,0};
  const int a0b = col*(KTOT/8), a1b = (16+col)*(KTOT/8);
  #pragma unroll
  for (int i=0;i<KT_SL;i++){
    bf16x8 a0 = AhV[a0b + (kt0+i)*4 + quad];
    bf16x8 a1 = AhV[a1b + (kt0+i)*4 + quad];
    acc0 = __builtin_amdgcn_mfma_f32_16x16x32_bf16(a0, bfr[i].v, acc0, 0,0,0);
    acc1 = __builtin_amdgcn_mfma_f32_16x16x32_bf16(a1, bfr[i].v, acc1, 0,0,0);
  }
  // partial slab: Pp[m(batch)][col(j within tile)]
  float* Pp = P + ((size_t)(jt*KSPLIT + kq)*4 + g)*512;
  const int rowd = quad*4;
  #pragma unroll
  for (int r=0;r<4;r++){
    Pp[(rowd+r)*16 + col]      = acc0[r];
    Pp[(16+rowd+r)*16 + col]   = acc1[r];
  }

  // ---- arrival: elect the last block for this j-tile ----
  __threadfence();                       // release partial slab
  if (tid==0) isred = (atomicAdd(&cnt[slot*NJT + jt], 1) == KSPLIT-1);
  __syncthreads();
  if (!isred) return;
  __threadfence();                       // acquire all 8 slabs

  // ---- cell for j in [jt*16, jt*16+16), all 32 batches (2 units/thread) ----
  const int j0 = jt*16;
  const int jj = tid & 15;
  float zpart[2], spart[2];
  #pragma unroll
  for (int unit=0; unit<2; unit++){
    const int b = (tid>>4) + unit*16;
    const int j = j0 + jj;
    float gv[4];
    #pragma unroll
    for (int g2=0; g2<4; g2++){
      float v = bias[g2*VOCAB + j];
      #pragma unroll
      for (int kq2=0; kq2<KSPLIT; kq2++)
        v += P[((size_t)(jt*KSPLIT + kq2)*4 + g2)*512 + b*16 + jj];
      gv[g2] = v;
    }
    float cold = c[b*VOCAB + j];
    float cn = sigmoidf_(gv[1])*cold + sigmoidf_(gv[0])*tanhf_(gv[2]);
    float hn = sigmoidf_(gv[3])*tanhf_(cn);
    const bool upd = tok[b*TT + (t-1)] != 0;
    float hf = upd ? hn : h[b*VOCAB + j];
    float cf = upd ? cn : cold;
    h[b*VOCAB + j] = hf;
    c[b*VOCAB + j] = cf;
    Ahb[b*KTOT + EMB + j] = f2bf(hf);
    const int sj = tok[b*TT + t];
    float e = __expf(hf);               // h in (-1,1): no max-pass needed
    if (j == sj) atomicAdd(&Eac[slot*32 + b], e);
    zpart[unit] = e;
    spart[unit] = (j < sj) ? e : 0.f;
  }
  #pragma unroll
  for (int m=1; m<16; m<<=1){
    zpart[0] += __shfl_xor(zpart[0], m);  spart[0] += __shfl_xor(spart[0], m);
    zpart[1] += __shfl_xor(zpart[1], m);  spart[1] += __shfl_xor(spart[1], m);
  }
  if (jj == 0){
    const int b1 = tid>>4;
    atomicAdd(&Zac[slot*32 + b1],      zpart[0]);
    atomicAdd(&Sac[slot*32 + b1],      spart[0]);
    atomicAdd(&Zac[slot*32 + b1 + 16], zpart[1]);
    atomicAdd(&Sac[slot*32 + b1 + 16], spart[1]);
  }
  if (jt < BATCH && t < TT-1)            // stage next step's x-row (b = jt)
    Ahb[jt*KTOT + tid] = f2bf(E[(size_t)tok[jt*TT + t]*EMB + tid]);

  // ---- second-level arrival: last reducer writes the output ----
  __threadfence();
  __syncthreads();
  if (tid==0) isfin = (atomicAdd(&cnt2[slot], 1) == NJT-1);
  __syncthreads();
  if (!isfin) return;
  __threadfence();
  if (tid < BATCH){
    float Z  = atomicAdd(&Zac[slot*32 + tid], 0.f);   // coherent read
    float S  = atomicAdd(&Sac[slot*32 + tid], 0.f);
    float Ej = atomicAdd(&Eac[slot*32 + tid], 0.f);
    vsh[tid] = (3.f*S + 1.5f*Ej)/Z;
  }
  __syncthreads();
  for (int i=tid; i<BATCH*LAT; i+=NTHR)
    out[(size_t)((i>>7)*TT + t)*LAT + (i&(LAT-1))] = vsh[i>>7];
}

extern "C" void kernel_launch(void* const* d_in, const int* in_sizes, int n_in,
                              void* d_out, int out_size, void* d_ws, size_t ws_size,
                              hipStream_t stream){
  const int*   tok  = (const int*)d_in[0];
  const float* E    = (const float*)d_in[1];
  const float* Wi   = (const float*)d_in[2];
  const float* Wh   = (const float*)d_in[3];
  const float* bias = (const float*)d_in[4];
  float* out = (float*)d_out;
  float* ws  = (float*)d_ws;
  float* P    = ws + P_OFF;
  float* h    = ws + H_OFF;
  float* c    = ws + C_OFF;
  float* Zac  = ws + ZAC_OFF;
  float* Sac  = ws + SAC_OFF;
  float* Eac  = ws + EAC_OFF;
  int*   cnt  = (int*)(ws + CNT_OFF);
  int*   cnt2 = (int*)(ws + CNT2_OFF);
  unsigned short* Ahb = (unsigned short*)(ws + AHB_OFF);
  unsigned short* Bp  = (unsigned short*)(ws + BP_OFF);

  k_init<<<288, NTHR, 0, stream>>>(tok, E, h, c, Zac, Sac, Eac, cnt, cnt2, Ahb, out);
  for (int t = 1; t < TT; t++){
    k_step<<<NJT*KSPLIT, NTHR, 0, stream>>>(tok, E, Wi, Wh, bias, out, P, h, c,
                                            Zac, Sac, Eac, cnt, cnt2, Ahb, Bp, t);
  }
}

// Round 9
// 235.099 us; speedup vs baseline: 7.5189x; 6.8482x over previous
//
#include <hip/hip_runtime.h>

#define BATCH 32
#define TT 8
#define VOCAB 2048
#define EMB 256
#define NG 8192          // 4*VOCAB
#define LAT 128
#define KTOT 2304        // EMB + VOCAB
#define NKT 72           // K-tiles of 32
#define NNT 512          // N-tiles of 16
#define KSPLIT 8
#define KT_PER 9         // NKT/KSPLIT
#define NTHR 256

typedef __bf16 bf16x8 __attribute__((ext_vector_type(8)));
typedef float  f32x4  __attribute__((ext_vector_type(4)));

// ws layout (float offsets)
#define P_OFF   0
#define P_SZ    (KSPLIT*BATCH*NG)     // 8 MB partial slabs
#define H_OFF   (P_OFF + P_SZ)
#define H_SZ    (BATCH*VOCAB)
#define C_OFF   (H_OFF + H_SZ)
#define C_SZ    (BATCH*VOCAB)
#define ST_OFF  (C_OFF + C_SZ)
#define ST_SZ   (BATCH*8*2)
#define ESJ_OFF (ST_OFF + ST_SZ)
#define ESJ_SZ  32
#define AHB_OFF (ESJ_OFF + ESJ_SZ)    // ushort region: 32*2304
#define AHB_SZF ((BATCH*KTOT)/2)
#define BP_OFF  (AHB_OFF + AHB_SZF)   // ushort region: 512*72*64*8 (~37.7MB)

__device__ __forceinline__ float sigmoidf_(float x){ return 1.f/(1.f+__expf(-x)); }
__device__ __forceinline__ float tanhf_(float x){
  x = fminf(fmaxf(x, -10.f), 10.f);
  float e = __expf(2.f*x);
  return (e-1.f)/(e+1.f);
}
__device__ __forceinline__ unsigned short f2bf(float f){   // round-to-nearest-even
  unsigned int u = __float_as_uint(f);
  return (unsigned short)((u + 0x7FFFu + ((u>>16)&1u)) >> 16);
}

// One-time: pack [Wi;Wh] fp32 -> bf16 MFMA B-fragment order, fused with state init.
// Bp[nt][kt][lane][j] = W[kt*32 + (lane>>4)*8 + j][nt*16 + (lane&15)]
__global__ __launch_bounds__(NTHR) void k_packinit(
    const int* __restrict__ tok, const float* __restrict__ E,
    const float* __restrict__ Wi, const float* __restrict__ Wh,
    unsigned short* __restrict__ Bp, float* __restrict__ h, float* __restrict__ c,
    unsigned short* __restrict__ Ahb, float* __restrict__ out){
  const int i = blockIdx.x*NTHR + threadIdx.x;     // [0, 512*72*64)
  {
    int lane = i & 63, kt = (i>>6) % NKT, nt = i/(64*NKT);
    int n = nt*16 + (lane & 15);
    int k0 = kt*32 + (lane>>4)*8;
    unsigned int u[4];
    #pragma unroll
    for (int p=0;p<4;p++){
      int ka = k0 + 2*p, kb = ka + 1;
      float fa = (ka < EMB) ? Wi[(size_t)ka*NG + n] : Wh[(size_t)(ka-EMB)*NG + n];
      float fb = (kb < EMB) ? Wi[(size_t)kb*NG + n] : Wh[(size_t)(kb-EMB)*NG + n];
      u[p] = (unsigned int)f2bf(fa) | ((unsigned int)f2bf(fb) << 16);
    }
    *(uint4*)&Bp[(size_t)i*8] = make_uint4(u[0],u[1],u[2],u[3]);
  }
  if (i < BATCH*VOCAB){ h[i] = 0.f; c[i] = 0.f; }
  if (i < BATCH*KTOT){
    int b = i / KTOT, k = i % KTOT;
    Ahb[i] = (k < EMB) ? f2bf(E[(size_t)tok[b*TT+0]*EMB + k]) : (unsigned short)0;
  }
  if (i < BATCH*LAT)
    out[(size_t)((i>>7)*TT + 0)*LAT + (i&(LAT-1))] = 0.f;  // t=0: rng=0 -> z=0
}

// P[kc] = [x|h](bf16) @ [Wi;Wh](bf16 packed) k-slice.
// Wave: M=32 x N=16 tile, 9 k-tiles, ALL 9 B-fragments preloaded (9 outstanding
// 1KB wave-loads) before the MFMA chain. Block = 4 waves = 4 consecutive nt,
// whole block one kc; kc = blockIdx.x & 7 pins each Bp slice to one XCD.
// Block 0 also finalizes the PREVIOUS step's output (t>=2).
__global__ __launch_bounds__(NTHR) void k_gemm(
    const unsigned short* __restrict__ Ahb, const unsigned short* __restrict__ Bp,
    float* __restrict__ P, const float* __restrict__ stats,
    const float* __restrict__ esj, float* __restrict__ out, int t){
  const int tid = threadIdx.x;

  if (blockIdx.x==0 && t>=2){    // block-uniform branch
    __shared__ float vsh[BATCH];
    if (tid < BATCH){
      float Z=0.f, S=0.f;
      #pragma unroll
      for (int jc=0;jc<8;jc++){ Z += stats[(tid*8+jc)*2]; S += stats[(tid*8+jc)*2+1]; }
      vsh[tid] = (3.f*S + 1.5f*esj[tid])/Z;
    }
    __syncthreads();
    for (int i=tid; i<BATCH*LAT; i+=NTHR)
      out[(size_t)((i>>7)*TT + (t-1))*LAT + (i&(LAT-1))] = vsh[i>>7];
  }

  const int w = tid >> 6, lane = tid & 63;
  const int quad = lane >> 4, col = lane & 15;
  const int kc = blockIdx.x & 7;                 // XCD-pinned k-slice
  const int nt = (blockIdx.x >> 3)*4 + w;        // [0, 512)
  const int kt0 = kc*KT_PER;
  const bf16x8* __restrict__ AhV = (const bf16x8*)Ahb;  // m*288 + kt*4 + quad
  const bf16x8* __restrict__ BpV = (const bf16x8*)Bp;   // (nt*NKT+kt)*64 + lane

  bf16x8 bfr[KT_PER];                            // 9 outstanding wave-loads
  #pragma unroll
  for (int i=0;i<KT_PER;i++)
    bfr[i] = BpV[((size_t)nt*NKT + kt0+i)*64 + lane];

  f32x4 acc0={0,0,0,0}, acc1={0,0,0,0};
  const int a0b = col*(KTOT/8), a1b = (16+col)*(KTOT/8);
  #pragma unroll
  for (int i=0;i<KT_PER;i++){
    bf16x8 a0 = AhV[a0b + (kt0+i)*4 + quad];
    bf16x8 a1 = AhV[a1b + (kt0+i)*4 + quad];
    acc0 = __builtin_amdgcn_mfma_f32_16x16x32_bf16(a0, bfr[i], acc0, 0,0,0);
    acc1 = __builtin_amdgcn_mfma_f32_16x16x32_bf16(a1, bfr[i], acc1, 0,0,0);
  }
  float* Pp = P + (size_t)kc*BATCH*NG;
  const int rowd = quad*4;
  #pragma unroll
  for (int r=0;r<4;r++){
    Pp[(size_t)(rowd+r)*NG    + nt*16 + col] = acc0[r];
    Pp[(size_t)(16+rowd+r)*NG + nt*16 + col] = acc1[r];
  }
}

// Reduce KSPLIT slabs + bias -> gates -> masked LSTM cell -> h,c -> bf16 h into
// Ahb; jc==0 blocks stage next step's x-row; partial softmax stats.
__global__ __launch_bounds__(NTHR) void k_cellred(
    const int* __restrict__ tok, const float* __restrict__ E,
    const float* __restrict__ bias, const float* __restrict__ P,
    float* __restrict__ h, float* __restrict__ c, unsigned short* __restrict__ Ahb,
    float* __restrict__ stats, float* __restrict__ esj, int t){
  const int tid = threadIdx.x;
  const int jc = blockIdx.x, b = blockIdx.y;
  const int j = jc*256 + tid;
  const int lane = tid & 63, wid = tid >> 6;

  float ip = bias[j], fp = bias[j+VOCAB], gg = bias[j+2*VOCAB], op = bias[j+3*VOCAB];
  #pragma unroll
  for (int kc=0;kc<KSPLIT;kc++){
    const float* Pp = P + (size_t)(kc*BATCH + b)*NG;
    ip += Pp[j]; fp += Pp[j+VOCAB]; gg += Pp[j+2*VOCAB]; op += Pp[j+3*VOCAB];
  }

  float cold = c[b*VOCAB + j];
  float cn = sigmoidf_(fp)*cold + sigmoidf_(ip)*tanhf_(gg);
  float hn = sigmoidf_(op)*tanhf_(cn);
  const bool upd = tok[b*TT + (t-1)] != 0;
  float hf = upd ? hn : h[b*VOCAB + j];
  float cf = upd ? cn : cold;
  h[b*VOCAB + j] = hf;
  c[b*VOCAB + j] = cf;
  Ahb[b*KTOT + EMB + j] = f2bf(hf);
  if (jc == 0 && t < TT-1)   // stage next step's x-row: x = E[tok[:,t]]
    Ahb[b*KTOT + tid] = f2bf(E[(size_t)tok[b*TT + t]*EMB + tid]);

  const int sj = tok[b*TT + t];
  float e = __expf(hf);                 // h in (-1,1): no max-pass needed
  float z = e, s = (j < sj) ? e : 0.f;
  if (j == sj) esj[b] = e;

  __shared__ float zsh[4], ssh[4];
  #pragma unroll
  for (int off=32; off; off>>=1){ z += __shfl_down(z, off); s += __shfl_down(s, off); }
  if (lane==0){ zsh[wid] = z; ssh[wid] = s; }
  __syncthreads();
  if (tid==0){
    stats[(b*8 + jc)*2 + 0] = zsh[0]+zsh[1]+zsh[2]+zsh[3];
    stats[(b*8 + jc)*2 + 1] = ssh[0]+ssh[1]+ssh[2]+ssh[3];
  }
}

// z[b,t,:] = (3*S + 1.5*e_sj)/Z  broadcast over LAT  (final step)
__global__ __launch_bounds__(NTHR) void k_out(
    const float* __restrict__ stats, const float* __restrict__ esj,
    float* __restrict__ out, int t){
  const int tid = threadIdx.x;
  __shared__ float vsh[BATCH];
  if (tid < BATCH){
    float Z=0.f, S=0.f;
    #pragma unroll
    for (int jc=0;jc<8;jc++){ Z += stats[(tid*8+jc)*2]; S += stats[(tid*8+jc)*2+1]; }
    vsh[tid] = (3.f*S + 1.5f*esj[tid])/Z;
  }
  __syncthreads();
  for (int i=tid; i<BATCH*LAT; i+=NTHR)
    out[(size_t)((i>>7)*TT + t)*LAT + (i&(LAT-1))] = vsh[i>>7];
}

extern "C" void kernel_launch(void* const* d_in, const int* in_sizes, int n_in,
                              void* d_out, int out_size, void* d_ws, size_t ws_size,
                              hipStream_t stream){
  const int*   tok  = (const int*)d_in[0];
  const float* E    = (const float*)d_in[1];
  const float* Wi   = (const float*)d_in[2];
  const float* Wh   = (const float*)d_in[3];
  const float* bias = (const float*)d_in[4];
  float* out = (float*)d_out;
  float* ws  = (float*)d_ws;
  float* P     = ws + P_OFF;
  float* h     = ws + H_OFF;
  float* c     = ws + C_OFF;
  float* stats = ws + ST_OFF;
  float* esj   = ws + ESJ_OFF;
  unsigned short* Ahb = (unsigned short*)(ws + AHB_OFF);
  unsigned short* Bp  = (unsigned short*)(ws + BP_OFF);

  k_packinit<<<(NNT*NKT*64)/NTHR, NTHR, 0, stream>>>(tok, E, Wi, Wh, Bp, h, c, Ahb, out);
  for (int t = 1; t < TT; t++){
    k_gemm<<<NNT*KSPLIT/4, NTHR, 0, stream>>>(Ahb, Bp, P, stats, esj, out, t);
    k_cellred<<<dim3(8, BATCH), NTHR, 0, stream>>>(tok, E, bias, P, h, c, Ahb, stats, esj, t);
  }
  k_out<<<1, NTHR, 0, stream>>>(stats, esj, out, TT-1);
}